// Round 6
// baseline (515.130 us; speedup 1.0000x reference)
//
#include <hip/hip_runtime.h>
#include <hip/hip_cooperative_groups.h>

namespace cg = cooperative_groups;

// OpeningP4: x [4,4,64,64,8] f32, kernel [3,3,3,8,16] f32 -> out [4,4,64,64,16] f32.
// v18 = COOPERATIVE FUSION. R5 diagnostic: E+D window = 31us (vs ~10us VALU floor);
// decomposition: 44us poison-fill + 31us E+D + ~19us harness (fixed). The excess is
// structural: 2 dependent dispatches (launch gap + inter-dispatch L2 flush of the
// 17.3MB ero intermediate) + serial stage->barrier->compute per kernel. Fix: ONE
// kernel, 512 blocks x 512 threads (exactly 2 blocks/CU, 4 waves/SIMD — NOT v15's
// 1-block/CU mistake), phase E (erosion, 2 rows/block) -> threadfence +
// grid.sync() -> phase D (dilation, j-split across thread bit 8).
// LDS: es 61.4KB overlays xs 26.1KB; kls 13.8KB separate; total 75.3KB (2/CU).
// Erosion/dilation algebra VERBATIM from PASSED v16. Fallback to v16 split kernels
// if hipLaunchCooperativeKernel returns error.

#define HH 64
#define WW 64
#define NEG_INF (-__builtin_inff())
#define POS_INF (__builtin_inff())

#define ROT_G(G, A, B, I, J) do { switch (G) { \
    case 0:  I = (A);     J = (B);     break; \
    case 1:  I = (B);     J = 2 - (A); break; \
    case 2:  I = 2 - (A); J = 2 - (B); break; \
    default: I = 2 - (B); J = (A);     break; } } while (0)

typedef _Float16 hv4 __attribute__((ext_vector_type(4)));   // 8 B, v_pk_* pairs

__device__ __forceinline__ hv4 f4_to_hv4(float4 v) {
    hv4 r;
    r.x = (_Float16)v.x; r.y = (_Float16)v.y;
    r.z = (_Float16)v.z; r.w = (_Float16)v.w;
    return r;
}

// ======================= fused cooperative kernel ================================
// grid 512 = b(4) x g|hs... phase E: b(4) x g(4) x h2(32), 2 rows each.
//            phase D: b(4) x hs(16) x ws(8), 4 out rows x 8 px, all 4 j.
__global__ __launch_bounds__(512, 4) void opening_coop(
    const float* __restrict__ x, const float* __restrict__ ker,
    hv4* __restrict__ ero, float* __restrict__ out)
{
    // union: phase E uses xs (26,112B) in the first part; phase D uses es (61,440B)
    __shared__ __align__(16) char smem[61440 + 13824];
    float*  xs  = (float*)smem;                  // [p(3)][r(4)][c(8)][68]
    hv4*    es  = (hv4*)smem;                    // [g(4)][ei(6)][wp10(10)][cq(32)]
    float4* kls = (float4*)(smem + 61440);       // raw ker, 864 float4

    const int tid = threadIdx.x;
    const int bid = blockIdx.x;

    const float4* ker4 = (const float4*)ker;
    for (int t = tid; t < 864; t += 512)
        kls[t] = ker4[t];

    // ======================= phase E: erosion, 2 rows/block ======================
    {
        const int h2 = bid & 31;
        const int g  = (bid >> 5) & 3;
        const int b  = bid >> 7;
        const int h0 = h2 * 2;

        const float4* x4 = (const float4*)x;
        // stage 3 planes x[(g+p-1)&3], rows h0-1..h0+2, cols -1..64, OOB=+inf
        for (int t = tid; t < 1584; t += 512) {
            int q01 = t & 1;
            int u = t >> 1;          // 0..791
            int wp = u % 66;
            int v = u / 66;          // 0..11
            int r = v & 3;
            int p = v >> 2;          // 0..2
            int g2 = (g + p + 3) & 3;
            int hh = h0 - 1 + r;
            int w2 = wp - 1;
            float4 vv;
            if ((unsigned)hh < HH && (unsigned)w2 < WW)
                vv = x4[(((b * 4 + g2) * HH + hh) * WW + w2) * 2 + q01];
            else
                vv = make_float4(POS_INF, POS_INF, POS_INF, POS_INF);
            int rowb = (p * 4 + r) * 8 + q01 * 4;
            xs[(rowb + 0) * 68 + wp] = vv.x;
            xs[(rowb + 1) * 68 + wp] = vv.y;
            xs[(rowb + 2) * 68 + wp] = vv.z;
            xs[(rowb + 3) * 68 + wp] = vv.w;
        }
        __syncthreads();

        const int lt   = tid & 255;
        const int r01  = tid >> 8;          // wave-uniform row select
        const int q    = lt & 3;
        const int c    = (lt >> 2) & 7;
        const int cq   = lt & 31;
        const int slot = lt >> 5;
        const float4* xs4 = (const float4*)xs;

        float4 acc[8];
#pragma unroll
        for (int i = 0; i < 8; ++i)
            acc[i] = make_float4(POS_INF, POS_INF, POS_INF, POS_INF);

#pragma unroll
        for (int k2 = 0; k2 < 3; ++k2) {
            // KE_g[dy,dx,k2,c,q] — VERBATIM erode_t algebra
            float4 ke9[9];
#pragma unroll
            for (int t9 = 0; t9 < 9; ++t9) {
                int dy = t9 / 3, dx = t9 % 3;
                int a0 = 2 - dy, b0 = 2 - dx;
                int i, jj;
                ROT_G(g, a0, b0, i, jj);
                int ka, kb, kc;
                if (k2 == 0)      { ka = 2 - jj; kb = i;      kc = 2; }
                else if (k2 == 1) { ka = i;      kb = jj;     kc = 1; }
                else              { ka = jj;     kb = 2 - i;  kc = 0; }
                ke9[t9] = kls[((ka * 3 + kb) * 3 + kc) * 32 + cq];
            }
#pragma unroll
            for (int dy = 0; dy < 3; ++dy) {
                // staged row for out row h0+r01, tap dy = r01+dy (0..3)
                const int base4 = ((k2 * 4 + r01 + dy) * 8 + c) * 17 + slot * 2;
                float4 xa = xs4[base4];
                float4 xb = xs4[base4 + 1];
                float4 xc = xs4[base4 + 2];
                float xw[12] = {xa.x, xa.y, xa.z, xa.w,
                                xb.x, xb.y, xb.z, xb.w,
                                xc.x, xc.y, xc.z, xc.w};
#pragma unroll
                for (int dx = 0; dx < 3; ++dx) {
                    float4 kv = ke9[dy * 3 + dx];
#pragma unroll
                    for (int i = 0; i < 8; ++i) {
                        float v = xw[i + dx];
                        acc[i].x = fminf(acc[i].x, v - kv.x);
                        acc[i].y = fminf(acc[i].y, v - kv.y);
                        acc[i].z = fminf(acc[i].z, v - kv.z);
                        acc[i].w = fminf(acc[i].w, v - kv.w);
                    }
                }
            }
        }

        // store: wp = slot*8 + i + 1 (VERBATIM erode_t layout)
        const int row = (b * 4 + g) * HH + h0 + r01;
        const size_t obase = ((size_t)row * 66 + slot * 8 + 1) * 32 + cq;
#pragma unroll
        for (int i = 0; i < 8; ++i)
            ero[obase + (size_t)i * 32] = f4_to_hv4(acc[i]);

        const hv4 ninfE = {(_Float16)NEG_INF, (_Float16)NEG_INF,
                           (_Float16)NEG_INF, (_Float16)NEG_INF};
        if (lt < 32)
            ero[(size_t)row * 66 * 32 + lt] = ninfE;
        else if (lt < 64)
            ero[((size_t)row * 66 + 65) * 32 + (lt - 32)] = ninfE;
    }

    __threadfence();            // device-scope release (cross-XCD L2 writeback)
    cg::this_grid().sync();     // grid-wide barrier
    __threadfence();            // device-scope acquire (invalidate stale lines)

    // ======================= phase D: dilation (j-split) =========================
    {
        const int ws_ = bid & 7;
        const int hs  = (bid >> 3) & 15;
        const int b   = bid >> 7;

        // stage ero: 3840 x 16B transfers, 7.5 per thread
        {
            const float4* ero4 = (const float4*)ero;
            float4* es4 = (float4*)es;
            const float nf = __uint_as_float(0xFC00FC00u);   // 2x f16 -inf
            const float4 ninf4 = make_float4(nf, nf, nf, nf);
            for (int t = tid; t < 3840; t += 512) {
                const int cq2 = t & 15;
                const int rest = t >> 4;          // (gsrc*6+ei)*10 + wp10
                const int wp10 = rest % 10;
                const int ge = rest / 10;
                const int ei = ge % 6;
                const int gsrc = ge / 6;
                const int er = hs * 4 - 1 + ei;
                float4 v = ninf4;
                if ((unsigned)er < HH)
                    v = ero4[(((b * 4 + gsrc) * HH + er) * 66 + ws_ * 8 + wp10) * 16 + cq2];
                es4[rest * 16 + cq2] = v;
            }
        }
        __syncthreads();

        const int lt   = tid & 255;
        const int jh   = tid >> 8;          // wave-uniform: j in {2jh, 2jh+1}
        const int q    = lt & 3;
        const int c    = (lt >> 2) & 7;
        const int cq   = lt & 31;
        const int slot = lt >> 5;

        const hv4 ninf = {(_Float16)NEG_INF, (_Float16)NEG_INF,
                          (_Float16)NEG_INF, (_Float16)NEG_INF};
        hv4 acc[2][4];                      // [jo][local row], statically indexed
#pragma unroll
        for (int jo = 0; jo < 2; ++jo)
#pragma unroll
            for (int r = 0; r < 4; ++r)
                acc[jo][r] = ninf;

#pragma unroll
        for (int jo = 0; jo < 2; ++jo) {
            const int j = jh * 2 + jo;
#pragma unroll
            for (int k = 0; k < 3; ++k) {
                const int gsrc = (j + k + 3) & 3;   // ep[:, j+k] wrap (v14-verified)
                hv4 kd9[9];
#pragma unroll
                for (int t9 = 0; t9 < 9; ++t9) {
                    int dy = t9 / 3, dx = t9 % 3;
                    int i, jj;
                    ROT_G(j, dy, dx, i, jj);
                    kd9[t9] = f4_to_hv4(kls[((i * 3 + jj) * 3 + k) * 32 + cq]);
                }
                const int pbase = gsrc * 1920 + slot * 32 + cq;
#pragma unroll
                for (int ei = 0; ei < 6; ++ei) {
                    const int rb = pbase + ei * 320;
                    hv4 e0 = es[rb];
                    hv4 e1 = es[rb + 32];
                    hv4 e2 = es[rb + 64];
#pragma unroll
                    for (int dy = 0; dy < 3; ++dy) {
                        const int rr = ei - dy;
                        if (rr < 0 || rr >= 4) continue;   // compile-time prune
                        acc[jo][rr] = __builtin_elementwise_max(acc[jo][rr],
                                                                e0 + kd9[dy * 3 + 0]);
                        acc[jo][rr] = __builtin_elementwise_max(acc[jo][rr],
                                                                e1 + kd9[dy * 3 + 1]);
                        acc[jo][rr] = __builtin_elementwise_max(acc[jo][rr],
                                                                e2 + kd9[dy * 3 + 2]);
                    }
                }
            }
        }

        // c-sum in f32 via xor-shuffle (c = lane bits 2..4), then store
        float4* out4 = (float4*)out;
        const int w = ws_ * 8 + slot;
#pragma unroll
        for (int jo = 0; jo < 2; ++jo) {
            const int j = jh * 2 + jo;
            const int rowb = (b * 4 + j) * HH + hs * 4;
#pragma unroll
            for (int rr = 0; rr < 4; ++rr) {
                float4 s = make_float4((float)acc[jo][rr].x, (float)acc[jo][rr].y,
                                       (float)acc[jo][rr].z, (float)acc[jo][rr].w);
#pragma unroll
                for (int off = 4; off <= 16; off <<= 1) {
                    s.x += __shfl_xor(s.x, off, 64);
                    s.y += __shfl_xor(s.y, off, 64);
                    s.z += __shfl_xor(s.z, off, 64);
                    s.w += __shfl_xor(s.w, off, 64);
                }
                if (c == 0)
                    out4[((size_t)(rowb + rr) * WW + w) * 4 + q] = s;
            }
        }
    }
}

// ======================= fallback kernel 1: erosion (v16, PASSED) =================
__global__ __launch_bounds__(256) void erode_t(const float* __restrict__ x,
                                               const float* __restrict__ ker,
                                               hv4* __restrict__ ero) {
    __shared__ __align__(16) float xs[9 * 8 * 68];
    __shared__ __align__(16) float4 kls[864];

    const int tid = threadIdx.x;
    const int h = blockIdx.x & 63;
    const int g = (blockIdx.x >> 6) & 3;
    const int b = blockIdx.x >> 8;

    const float4* x4 = (const float4*)x;
    const float4* ker4 = (const float4*)ker;

    for (int t = tid; t < 864; t += 256)
        kls[t] = ker4[t];

    for (int t = tid; t < 1188; t += 256) {
        int q01 = t & 1;
        int u = t >> 1;
        int wp = u % 66;
        int v = u / 66;
        int r = v % 3;
        int p = v / 3;
        int g2 = (g + p + 3) & 3;
        int h2 = h - 1 + r;
        int w2 = wp - 1;
        float4 vv;
        if ((unsigned)h2 < HH && (unsigned)w2 < WW)
            vv = x4[(((b * 4 + g2) * HH + h2) * WW + w2) * 2 + q01];
        else
            vv = make_float4(POS_INF, POS_INF, POS_INF, POS_INF);
        int rowb = (p * 3 + r) * 8 + q01 * 4;
        xs[(rowb + 0) * 68 + wp] = vv.x;
        xs[(rowb + 1) * 68 + wp] = vv.y;
        xs[(rowb + 2) * 68 + wp] = vv.z;
        xs[(rowb + 3) * 68 + wp] = vv.w;
    }
    __syncthreads();

    const int q = tid & 3;
    const int c = (tid >> 2) & 7;
    const int slot = tid >> 5;
    const float4* xs4 = (const float4*)xs;

    float4 acc[8];
#pragma unroll
    for (int i = 0; i < 8; ++i)
        acc[i] = make_float4(POS_INF, POS_INF, POS_INF, POS_INF);

#pragma unroll
    for (int k2 = 0; k2 < 3; ++k2) {
        float4 ke9[9];
#pragma unroll
        for (int t9 = 0; t9 < 9; ++t9) {
            int dy = t9 / 3, dx = t9 % 3;
            int a0 = 2 - dy, b0 = 2 - dx;
            int i, jj;
            ROT_G(g, a0, b0, i, jj);
            int ka, kb, kc;
            if (k2 == 0)      { ka = 2 - jj; kb = i;      kc = 2; }
            else if (k2 == 1) { ka = i;      kb = jj;     kc = 1; }
            else              { ka = jj;     kb = 2 - i;  kc = 0; }
            ke9[t9] = kls[((ka * 3 + kb) * 3 + kc) * 32 + c * 4 + q];
        }
#pragma unroll
        for (int dy = 0; dy < 3; ++dy) {
            const int base4 = ((k2 * 3 + dy) * 8 + c) * 17 + slot * 2;
            float4 xa = xs4[base4];
            float4 xb = xs4[base4 + 1];
            float4 xc = xs4[base4 + 2];
            float xw[12] = {xa.x, xa.y, xa.z, xa.w,
                            xb.x, xb.y, xb.z, xb.w,
                            xc.x, xc.y, xc.z, xc.w};
#pragma unroll
            for (int dx = 0; dx < 3; ++dx) {
                float4 kv = ke9[dy * 3 + dx];
#pragma unroll
                for (int i = 0; i < 8; ++i) {
                    float v = xw[i + dx];
                    acc[i].x = fminf(acc[i].x, v - kv.x);
                    acc[i].y = fminf(acc[i].y, v - kv.y);
                    acc[i].z = fminf(acc[i].z, v - kv.z);
                    acc[i].w = fminf(acc[i].w, v - kv.w);
                }
            }
        }
    }

    const int row = (b * 4 + g) * HH + h;
    const size_t obase = ((size_t)row * 66 + slot * 8 + 1) * 32 + c * 4 + q;
#pragma unroll
    for (int i = 0; i < 8; ++i)
        ero[obase + (size_t)i * 32] = f4_to_hv4(acc[i]);

    const hv4 ninf = {(_Float16)NEG_INF, (_Float16)NEG_INF,
                      (_Float16)NEG_INF, (_Float16)NEG_INF};
    if (tid < 32)
        ero[(size_t)row * 66 * 32 + tid] = ninf;
    else if (tid < 64)
        ero[((size_t)row * 66 + 65) * 32 + (tid - 32)] = ninf;
}

// ======================= fallback kernel 2: dilation (v16, PASSED) ================
__global__ __launch_bounds__(256) void dilate_t2(const hv4* __restrict__ ero,
                                                 const float* __restrict__ ker,
                                                 float* __restrict__ out) {
    __shared__ __align__(16) hv4 es[4 * 6 * 10 * 32];
    __shared__ __align__(16) float4 kls[864];

    const int tid = threadIdx.x;
    const int ws = blockIdx.x & 7;
    const int hs = (blockIdx.x >> 3) & 15;
    const int b = blockIdx.x >> 7;

    const float4* ker4 = (const float4*)ker;

    for (int t = tid; t < 864; t += 256)
        kls[t] = ker4[t];

    {
        const float4* ero4 = (const float4*)ero;
        float4* es4 = (float4*)es;
        const float nf = __uint_as_float(0xFC00FC00u);
        const float4 ninf4 = make_float4(nf, nf, nf, nf);
        for (int t = tid; t < 3840; t += 256) {
            const int cq2 = t & 15;
            const int rest = t >> 4;
            const int wp10 = rest % 10;
            const int ge = rest / 10;
            const int ei = ge % 6;
            const int gsrc = ge / 6;
            const int er = hs * 4 - 1 + ei;
            float4 v = ninf4;
            if ((unsigned)er < HH)
                v = ero4[(((b * 4 + gsrc) * HH + er) * 66 + ws * 8 + wp10) * 16 + cq2];
            es4[rest * 16 + cq2] = v;
        }
    }
    __syncthreads();

    const int q = tid & 3;
    const int c = (tid >> 2) & 7;
    const int cq = tid & 31;
    const int slot = tid >> 5;

    const hv4 ninf = {(_Float16)NEG_INF, (_Float16)NEG_INF,
                      (_Float16)NEG_INF, (_Float16)NEG_INF};
    hv4 acc[4][4];
#pragma unroll
    for (int j = 0; j < 4; ++j)
#pragma unroll
        for (int r = 0; r < 4; ++r)
            acc[j][r] = ninf;

#pragma unroll
    for (int j = 0; j < 4; ++j) {
#pragma unroll
        for (int k = 0; k < 3; ++k) {
            const int gsrc = (j + k + 3) & 3;
            hv4 kd9[9];
#pragma unroll
            for (int t9 = 0; t9 < 9; ++t9) {
                int dy = t9 / 3, dx = t9 % 3;
                int i, jj;
                ROT_G(j, dy, dx, i, jj);
                kd9[t9] = f4_to_hv4(kls[((i * 3 + jj) * 3 + k) * 32 + cq]);
            }
            const int pbase = gsrc * 1920 + slot * 32 + cq;
#pragma unroll
            for (int ei = 0; ei < 6; ++ei) {
                const int rb = pbase + ei * 320;
                hv4 e0 = es[rb];
                hv4 e1 = es[rb + 32];
                hv4 e2 = es[rb + 64];
#pragma unroll
                for (int dy = 0; dy < 3; ++dy) {
                    const int rr = ei - dy;
                    if (rr < 0 || rr >= 4) continue;
                    acc[j][rr] = __builtin_elementwise_max(acc[j][rr], e0 + kd9[dy * 3 + 0]);
                    acc[j][rr] = __builtin_elementwise_max(acc[j][rr], e1 + kd9[dy * 3 + 1]);
                    acc[j][rr] = __builtin_elementwise_max(acc[j][rr], e2 + kd9[dy * 3 + 2]);
                }
            }
        }
    }

    float4* out4 = (float4*)out;
    const int w = ws * 8 + slot;
#pragma unroll
    for (int j = 0; j < 4; ++j) {
        const int rowb = (b * 4 + j) * HH + hs * 4;
#pragma unroll
        for (int rr = 0; rr < 4; ++rr) {
            float4 s = make_float4((float)acc[j][rr].x, (float)acc[j][rr].y,
                                   (float)acc[j][rr].z, (float)acc[j][rr].w);
#pragma unroll
            for (int off = 4; off <= 16; off <<= 1) {
                s.x += __shfl_xor(s.x, off, 64);
                s.y += __shfl_xor(s.y, off, 64);
                s.z += __shfl_xor(s.z, off, 64);
                s.w += __shfl_xor(s.w, off, 64);
            }
            if (c == 0)
                out4[((size_t)(rowb + rr) * WW + w) * 4 + q] = s;
        }
    }
}

extern "C" void kernel_launch(void* const* d_in, const int* in_sizes, int n_in,
                              void* d_out, int out_size, void* d_ws, size_t ws_size,
                              hipStream_t stream) {
    const float* x = (const float*)d_in[0];
    const float* ker = (const float*)d_in[1];
    float* out = (float*)d_out;

    const size_t ero_f16_bytes = (size_t)16 * HH * 66 * 32 * 8;   // 17,301,504
    hv4* ero = (hv4*)d_ws;

    bool done = false;
    if (ws_size >= ero_f16_bytes) {
        void* args[] = {(void*)&x, (void*)&ker, (void*)&ero, (void*)&out};
        hipError_t e = hipLaunchCooperativeKernel(
            reinterpret_cast<const void*>(opening_coop),
            dim3(512), dim3(512), args, 0, stream);
        if (e == hipSuccess) {
            done = true;
        } else {
            (void)hipGetLastError();   // clear sticky error, fall through to split
        }
    }
    if (!done && ws_size >= ero_f16_bytes) {
        erode_t<<<1024, 256, 0, stream>>>(x, ker, ero);
        dilate_t2<<<512, 256, 0, stream>>>(ero, ker, out);
    }
}

// Round 8
// 95.258 us; speedup vs baseline: 5.4078x; 5.4078x over previous
//
#include <hip/hip_runtime.h>

// OpeningP4: x [4,4,64,64,8] f32, kernel [3,3,3,8,16] f32 -> out [4,4,64,64,16] f32.
// v20 = v16 split pipeline with erode upgraded to 2 rows/block (structure proven
// correct inside v18 coop run, absmax 0.0625). Coop fusion ABANDONED: v18 spilled
// (64-VGPR clamp, 448us), v19 hung (no clamp -> >128 VGPR -> 1 block/CU -> grid.sync
// deadlock). erode2: 512 blocks x 512 thr, stages 12 halo rows per 2 computed rows
// (was 9 per 1), ker-LDS stage halved (512 vs 1024 blocks); LDS 39.9KB -> 4 blk/CU.
// dilate_t2 byte-identical v16 (PASSED). Fallback = v15 fused (PASSED, ws-free).
// NOTE: harness poison-fill of d_ws (268MB, 44us) + ~19us resets are fixed overhead;
// R5 diagnostic put E+D+2gaps at ~31us — this attacks E's staging share.

#define HH 64
#define WW 64
#define NEG_INF (-__builtin_inff())
#define POS_INF (__builtin_inff())

#define ROT_G(G, A, B, I, J) do { switch (G) { \
    case 0:  I = (A);     J = (B);     break; \
    case 1:  I = (B);     J = 2 - (A); break; \
    case 2:  I = 2 - (A); J = 2 - (B); break; \
    default: I = 2 - (B); J = (A);     break; } } while (0)

typedef _Float16 hv4 __attribute__((ext_vector_type(4)));   // 8 B, v_pk_* pairs

__device__ __forceinline__ hv4 f4_to_hv4(float4 v) {
    hv4 r;
    r.x = (_Float16)v.x; r.y = (_Float16)v.y;
    r.z = (_Float16)v.z; r.w = (_Float16)v.w;
    return r;
}

// ======================= kernel 1: erosion, 2 rows/block ==========================
// block = (b,g,h2); 512 threads: lt = (slot,c,q) over 256, r01 = tid>>8 row select.
// ero layout (hv4 elems): ((bg*64+h)*66 + wp)*32 + c*4 + q, wp = w+1, -inf borders.
// Algebra/staging/store VERBATIM from v18 phase E (PASSED absmax 0.0625).
__global__ __launch_bounds__(512) void erode2(const float* __restrict__ x,
                                              const float* __restrict__ ker,
                                              hv4* __restrict__ ero) {
    __shared__ __align__(16) float xs[12 * 8 * 68];   // 26,112 B
    __shared__ __align__(16) float4 kls[864];         // raw ker, 13,824 B

    const int tid = threadIdx.x;
    const int h2 = blockIdx.x & 31;
    const int g  = (blockIdx.x >> 5) & 3;
    const int b  = blockIdx.x >> 7;
    const int h0 = h2 * 2;

    const float4* x4 = (const float4*)x;
    const float4* ker4 = (const float4*)ker;

    for (int t = tid; t < 864; t += 512)
        kls[t] = ker4[t];

    // stage 3 planes x[(g+p-1)&3], rows h0-1..h0+2, cols -1..64 (wp 0..65), OOB=+inf
    for (int t = tid; t < 1584; t += 512) {
        int q01 = t & 1;
        int u = t >> 1;          // 0..791
        int wp = u % 66;
        int v = u / 66;          // 0..11
        int r = v & 3;
        int p = v >> 2;          // 0..2
        int g2 = (g + p + 3) & 3;
        int hh = h0 - 1 + r;
        int w2 = wp - 1;
        float4 vv;
        if ((unsigned)hh < HH && (unsigned)w2 < WW)
            vv = x4[(((b * 4 + g2) * HH + hh) * WW + w2) * 2 + q01];
        else
            vv = make_float4(POS_INF, POS_INF, POS_INF, POS_INF);
        int rowb = (p * 4 + r) * 8 + q01 * 4;
        xs[(rowb + 0) * 68 + wp] = vv.x;
        xs[(rowb + 1) * 68 + wp] = vv.y;
        xs[(rowb + 2) * 68 + wp] = vv.z;
        xs[(rowb + 3) * 68 + wp] = vv.w;
    }
    __syncthreads();

    const int lt   = tid & 255;
    const int r01  = tid >> 8;          // wave-uniform row select
    const int cq   = lt & 31;
    const int c    = (lt >> 2) & 7;
    const int slot = lt >> 5;
    const float4* xs4 = (const float4*)xs;

    float4 acc[8];
#pragma unroll
    for (int i = 0; i < 8; ++i)
        acc[i] = make_float4(POS_INF, POS_INF, POS_INF, POS_INF);

#pragma unroll
    for (int k2 = 0; k2 < 3; ++k2) {
#pragma unroll
        for (int dy = 0; dy < 3; ++dy) {
            // ke3: taps for this (k2,dy) — identical indices to PASSED ke9 algebra,
            // loaded per-dy to keep live VGPRs low (no spill at 512 threads).
            float4 ke3[3];
#pragma unroll
            for (int dx = 0; dx < 3; ++dx) {
                int a0 = 2 - dy, b0 = 2 - dx;
                int i, jj;
                ROT_G(g, a0, b0, i, jj);
                int ka, kb, kc;
                if (k2 == 0)      { ka = 2 - jj; kb = i;      kc = 2; }
                else if (k2 == 1) { ka = i;      kb = jj;     kc = 1; }
                else              { ka = jj;     kb = 2 - i;  kc = 0; }
                ke3[dx] = kls[((ka * 3 + kb) * 3 + kc) * 32 + cq];
            }
            // staged row for out row h0+r01, tap row = r01+dy (0..3)
            const int base4 = ((k2 * 4 + r01 + dy) * 8 + c) * 17 + slot * 2;
            float4 xa = xs4[base4];
            float4 xb = xs4[base4 + 1];
            float4 xc = xs4[base4 + 2];
            float xw[12] = {xa.x, xa.y, xa.z, xa.w,
                            xb.x, xb.y, xb.z, xb.w,
                            xc.x, xc.y, xc.z, xc.w};
#pragma unroll
            for (int dx = 0; dx < 3; ++dx) {
                float4 kv = ke3[dx];
#pragma unroll
                for (int i = 0; i < 8; ++i) {
                    float v = xw[i + dx];   // tap wp = slot*8 + i + dx
                    acc[i].x = fminf(acc[i].x, v - kv.x);
                    acc[i].y = fminf(acc[i].y, v - kv.y);
                    acc[i].z = fminf(acc[i].z, v - kv.z);
                    acc[i].w = fminf(acc[i].w, v - kv.w);
                }
            }
        }
    }

    // store: wp = slot*8 + i + 1 (VERBATIM layout); borders per row
    const int row = (b * 4 + g) * HH + h0 + r01;
    const size_t obase = ((size_t)row * 66 + slot * 8 + 1) * 32 + cq;
#pragma unroll
    for (int i = 0; i < 8; ++i)
        ero[obase + (size_t)i * 32] = f4_to_hv4(acc[i]);

    const hv4 ninf = {(_Float16)NEG_INF, (_Float16)NEG_INF,
                      (_Float16)NEG_INF, (_Float16)NEG_INF};
    if (lt < 32)
        ero[(size_t)row * 66 * 32 + lt] = ninf;
    else if (lt < 64)
        ero[((size_t)row * 66 + 65) * 32 + (lt - 32)] = ninf;
}

// ======================= kernel 2: dilation (v16, PASSED, byte-identical) =========
__global__ __launch_bounds__(256) void dilate_t2(const hv4* __restrict__ ero,
                                                 const float* __restrict__ ker,
                                                 float* __restrict__ out) {
    __shared__ __align__(16) hv4 es[4 * 6 * 10 * 32];   // 61,440 B
    __shared__ __align__(16) float4 kls[864];           // raw ker, 13,824 B

    const int tid = threadIdx.x;
    const int ws = blockIdx.x & 7;
    const int hs = (blockIdx.x >> 3) & 15;
    const int b = blockIdx.x >> 7;

    const float4* ker4 = (const float4*)ker;

    for (int t = tid; t < 864; t += 256)
        kls[t] = ker4[t];

    {
        const float4* ero4 = (const float4*)ero;
        float4* es4 = (float4*)es;
        const float nf = __uint_as_float(0xFC00FC00u);   // 2x f16 -inf
        const float4 ninf4 = make_float4(nf, nf, nf, nf);
        for (int t = tid; t < 3840; t += 256) {
            const int cq2 = t & 15;
            const int rest = t >> 4;
            const int wp10 = rest % 10;
            const int ge = rest / 10;
            const int ei = ge % 6;
            const int gsrc = ge / 6;
            const int er = hs * 4 - 1 + ei;
            float4 v = ninf4;
            if ((unsigned)er < HH)
                v = ero4[(((b * 4 + gsrc) * HH + er) * 66 + ws * 8 + wp10) * 16 + cq2];
            es4[rest * 16 + cq2] = v;
        }
    }
    __syncthreads();

    const int q = tid & 3;
    const int c = (tid >> 2) & 7;
    const int cq = tid & 31;
    const int slot = tid >> 5;

    const hv4 ninf = {(_Float16)NEG_INF, (_Float16)NEG_INF,
                      (_Float16)NEG_INF, (_Float16)NEG_INF};
    hv4 acc[4][4];
#pragma unroll
    for (int j = 0; j < 4; ++j)
#pragma unroll
        for (int r = 0; r < 4; ++r)
            acc[j][r] = ninf;

#pragma unroll
    for (int j = 0; j < 4; ++j) {
#pragma unroll
        for (int k = 0; k < 3; ++k) {
            const int gsrc = (j + k + 3) & 3;   // ep[:, j+k] wrap (v14-verified)
            hv4 kd9[9];
#pragma unroll
            for (int t9 = 0; t9 < 9; ++t9) {
                int dy = t9 / 3, dx = t9 % 3;
                int i, jj;
                ROT_G(j, dy, dx, i, jj);
                kd9[t9] = f4_to_hv4(kls[((i * 3 + jj) * 3 + k) * 32 + cq]);
            }
            const int pbase = gsrc * 1920 + slot * 32 + cq;
#pragma unroll
            for (int ei = 0; ei < 6; ++ei) {
                const int rb = pbase + ei * 320;
                hv4 e0 = es[rb];
                hv4 e1 = es[rb + 32];
                hv4 e2 = es[rb + 64];
#pragma unroll
                for (int dy = 0; dy < 3; ++dy) {
                    const int rr = ei - dy;
                    if (rr < 0 || rr >= 4) continue;
                    acc[j][rr] = __builtin_elementwise_max(acc[j][rr], e0 + kd9[dy * 3 + 0]);
                    acc[j][rr] = __builtin_elementwise_max(acc[j][rr], e1 + kd9[dy * 3 + 1]);
                    acc[j][rr] = __builtin_elementwise_max(acc[j][rr], e2 + kd9[dy * 3 + 2]);
                }
            }
        }
    }

    float4* out4 = (float4*)out;
    const int w = ws * 8 + slot;
#pragma unroll
    for (int j = 0; j < 4; ++j) {
        const int rowb = (b * 4 + j) * HH + hs * 4;
#pragma unroll
        for (int rr = 0; rr < 4; ++rr) {
            float4 s = make_float4((float)acc[j][rr].x, (float)acc[j][rr].y,
                                   (float)acc[j][rr].z, (float)acc[j][rr].w);
#pragma unroll
            for (int off = 4; off <= 16; off <<= 1) {
                s.x += __shfl_xor(s.x, off, 64);
                s.y += __shfl_xor(s.y, off, 64);
                s.z += __shfl_xor(s.z, off, 64);
                s.w += __shfl_xor(s.w, off, 64);
            }
            if (c == 0)
                out4[((size_t)(rowb + rr) * WW + w) * 4 + q] = s;
        }
    }
}

// ============== fallback: v15 fused (PASSED, ws-free, 102us kernel) ==============
__global__ __launch_bounds__(512, 2) void opening_fused_v15(
    const float* __restrict__ x, const float* __restrict__ ker,
    float* __restrict__ out)
{
    __shared__ __align__(16) float xs[4 * 8 * 148];          // 18,944 B
    __shared__ __align__(16) hv4  es[4 * 10 * 10 * 32];      // 102,400 B

    const int tid = threadIdx.x;
    const int tx = blockIdx.x & 7;
    const int ty = (blockIdx.x >> 3) & 7;
    const int b  = blockIdx.x >> 6;

    const float4* x4 = (const float4*)x;
    const float4* ker4 = (const float4*)ker;

    for (int t = tid; t < 1152; t += 512) {
        int q01 = t & 1;
        int cell = t >> 1;
        int g = cell / 144;
        int rem = cell - g * 144;
        int r = rem / 12;
        int s = rem - r * 12;
        int h = ty * 8 - 2 + r;
        int w = tx * 8 - 2 + s;
        float4 v;
        if ((unsigned)h < HH && (unsigned)w < WW)
            v = x4[(((b * 4 + g) * HH + h) * WW + w) * 2 + q01];
        else
            v = make_float4(POS_INF, POS_INF, POS_INF, POS_INF);
        int pb = (g * 8 + q01 * 4) * 148 + rem;
        xs[pb]           = v.x;
        xs[pb + 148]     = v.y;
        xs[pb + 2 * 148] = v.z;
        xs[pb + 3 * 148] = v.w;
    }
    __syncthreads();

    const hv4 ninf = {(_Float16)NEG_INF, (_Float16)NEG_INF,
                      (_Float16)NEG_INF, (_Float16)NEG_INF};

    {
        const int cq   = tid & 31;
        const int c    = (tid >> 2) & 7;
        const int eyh5 = ((tid >> 5) & 1) * 5;
        const int g    = (tid >> 6) & 3;
        const int half = tid >> 8;
        const int ex0  = half * 5;
        const float4* xs4 = (const float4*)xs;

        float4 acc[5][5];
#pragma unroll
        for (int a = 0; a < 5; ++a)
#pragma unroll
            for (int p = 0; p < 5; ++p)
                acc[a][p] = make_float4(POS_INF, POS_INF, POS_INF, POS_INF);

#pragma unroll
        for (int k2 = 0; k2 < 3; ++k2) {
            float4 ke9[9];
#pragma unroll
            for (int t9 = 0; t9 < 9; ++t9) {
                int dy = t9 / 3, dx = t9 % 3;
                int a0 = 2 - dy, b0 = 2 - dx;
                int i, jj;
                ROT_G(g, a0, b0, i, jj);
                int ka, kb, kc;
                if (k2 == 0)      { ka = 2 - jj; kb = i;      kc = 2; }
                else if (k2 == 1) { ka = i;      kb = jj;     kc = 1; }
                else              { ka = jj;     kb = 2 - i;  kc = 0; }
                ke9[t9] = ker4[((ka * 3 + kb) * 3 + kc) * 32 + cq];
            }
            const int g2 = (g + k2 + 3) & 3;
            const int pb4 = (g2 * 8 + c) * 37;
#pragma unroll
            for (int el = 0; el < 5; ++el) {
#pragma unroll
                for (int dy = 0; dy < 3; ++dy) {
                    const int rowb = pb4 + (eyh5 + el + dy) * 3;
                    float w7[7];
                    if (half == 0) {
                        float4 xa = xs4[rowb], xb = xs4[rowb + 1];
                        w7[0] = xa.x; w7[1] = xa.y; w7[2] = xa.z; w7[3] = xa.w;
                        w7[4] = xb.x; w7[5] = xb.y; w7[6] = xb.z;
                    } else {
                        float4 xb = xs4[rowb + 1], xc = xs4[rowb + 2];
                        w7[0] = xb.y; w7[1] = xb.z; w7[2] = xb.w;
                        w7[3] = xc.x; w7[4] = xc.y; w7[5] = xc.z; w7[6] = xc.w;
                    }
#pragma unroll
                    for (int dx = 0; dx < 3; ++dx) {
                        float4 kv = ke9[dy * 3 + dx];
#pragma unroll
                        for (int px = 0; px < 5; ++px) {
                            float v = w7[px + dx];
                            acc[el][px].x = fminf(acc[el][px].x, v - kv.x);
                            acc[el][px].y = fminf(acc[el][px].y, v - kv.y);
                            acc[el][px].z = fminf(acc[el][px].z, v - kv.z);
                            acc[el][px].w = fminf(acc[el][px].w, v - kv.w);
                        }
                    }
                }
            }
        }
        const int hb = ty * 8 - 1 + eyh5;
        const int wb = tx * 8 - 1 + ex0;
        const int ebase = g * 3200 + eyh5 * 320 + ex0 * 32 + cq;
#pragma unroll
        for (int el = 0; el < 5; ++el)
#pragma unroll
            for (int px = 0; px < 5; ++px) {
                bool ok = ((unsigned)(hb + el) < HH) && ((unsigned)(wb + px) < WW);
                es[ebase + el * 320 + px * 32] =
                    ok ? f4_to_hv4(acc[el][px]) : ninf;
            }
    }
    __syncthreads();

    {
        const int q = tid & 3;
        const int c = (tid >> 2) & 7;
        const int cq = tid & 31;
        const int slot = (tid >> 5) & 7;
        const int rhalf = tid >> 8;

        hv4 acc[4][4];
#pragma unroll
        for (int j = 0; j < 4; ++j)
#pragma unroll
            for (int r = 0; r < 4; ++r)
                acc[j][r] = ninf;

#pragma unroll
        for (int j = 0; j < 4; ++j) {
#pragma unroll
            for (int k = 0; k < 3; ++k) {
                const int gsrc = (j + k + 3) & 3;
                hv4 kd9[9];
#pragma unroll
                for (int t9 = 0; t9 < 9; ++t9) {
                    int dy = t9 / 3, dx = t9 % 3;
                    int i, jj;
                    ROT_G(j, dy, dx, i, jj);
                    kd9[t9] = f4_to_hv4(ker4[((i * 3 + jj) * 3 + k) * 32 + cq]);
                }
                const int pbase = gsrc * 3200 + rhalf * 1280 + slot * 32 + cq;
#pragma unroll
                for (int ei = 0; ei < 6; ++ei) {
                    const int rb = pbase + ei * 320;
                    hv4 e0 = es[rb];
                    hv4 e1 = es[rb + 32];
                    hv4 e2 = es[rb + 64];
#pragma unroll
                    for (int dy = 0; dy < 3; ++dy) {
                        const int rr = ei - dy;
                        if (rr < 0 || rr >= 4) continue;
                        acc[j][rr] = __builtin_elementwise_max(acc[j][rr],
                                                               e0 + kd9[dy * 3 + 0]);
                        acc[j][rr] = __builtin_elementwise_max(acc[j][rr],
                                                               e1 + kd9[dy * 3 + 1]);
                        acc[j][rr] = __builtin_elementwise_max(acc[j][rr],
                                                               e2 + kd9[dy * 3 + 2]);
                    }
                }
            }
        }

        float4* out4 = (float4*)out;
        const int w = tx * 8 + slot;
#pragma unroll
        for (int j = 0; j < 4; ++j) {
            const int rowb = (b * 4 + j) * HH + ty * 8 + rhalf * 4;
#pragma unroll
            for (int rr = 0; rr < 4; ++rr) {
                float4 s = make_float4((float)acc[j][rr].x, (float)acc[j][rr].y,
                                       (float)acc[j][rr].z, (float)acc[j][rr].w);
#pragma unroll
                for (int off = 4; off <= 16; off <<= 1) {
                    s.x += __shfl_xor(s.x, off, 64);
                    s.y += __shfl_xor(s.y, off, 64);
                    s.z += __shfl_xor(s.z, off, 64);
                    s.w += __shfl_xor(s.w, off, 64);
                }
                if (c == 0)
                    out4[((size_t)(rowb + rr) * WW + w) * 4 + q] = s;
            }
        }
    }
}

extern "C" void kernel_launch(void* const* d_in, const int* in_sizes, int n_in,
                              void* d_out, int out_size, void* d_ws, size_t ws_size,
                              hipStream_t stream) {
    const float* x = (const float*)d_in[0];
    const float* ker = (const float*)d_in[1];
    float* out = (float*)d_out;

    const size_t ero_f16_bytes = (size_t)16 * HH * 66 * 32 * 8;   // 17,301,504

    if (ws_size >= ero_f16_bytes) {
        hv4* ero = (hv4*)d_ws;
        erode2<<<512, 512, 0, stream>>>(x, ker, ero);
        dilate_t2<<<512, 256, 0, stream>>>(ero, ker, out);
    } else {
        opening_fused_v15<<<256, 512, 0, stream>>>(x, ker, out);
    }
}

// Round 9
// 91.010 us; speedup vs baseline: 5.6602x; 1.0467x over previous
//
#include <hip/hip_runtime.h>

// OpeningP4: x [4,4,64,64,8] f32, kernel [3,3,3,8,16] f32 -> out [4,4,64,64,16] f32.
// v21 = VERBATIM RESTORE of v12 (best measured: 91.6us, prior session + R0).
// Session findings (R0-R8): the timed iteration decomposes as 44us poison-fill
// (HBM-bound, 77% peak — at roofline itself) + ~20us harness resets (fixed) +
// ~27us E+D (R5 dup-launch diagnostic). Six interventions on E+D all null/negative:
//   dilate traffic x6 cut (null), full fusion (+60us, occupancy), ker-LDS (null),
//   coop fusion (spill 448us / grid.sync deadlock), 2-row erode (+1.6us).
// E+D is latency-structured at this tiny problem size; throughput fixes don't bite,
// and fusion trades away occupancy. v12 pair is the plateau configuration.

#define HH 64
#define WW 64
#define NEG_INF (-__builtin_inff())
#define POS_INF (__builtin_inff())

#define ROT_G(G, A, B, I, J) do { switch (G) { \
    case 0:  I = (A);     J = (B);     break; \
    case 1:  I = (B);     J = 2 - (A); break; \
    case 2:  I = 2 - (A); J = 2 - (B); break; \
    default: I = 2 - (B); J = (A);     break; } } while (0)

typedef _Float16 hv4 __attribute__((ext_vector_type(4)));   // 8 B, v_pk_* pairs

__device__ __forceinline__ hv4 f4_to_hv4(float4 v) {
    hv4 r;
    r.x = (_Float16)v.x; r.y = (_Float16)v.y;
    r.z = (_Float16)v.z; r.w = (_Float16)v.w;
    return r;
}

// ======================= kernel 1: erosion (f32 math, f16 store) ==================
// block = (b,g,h); thread = (slot,c,q); pixels w = slot*8 + i, i=0..7 (consecutive).
// ero layout (hv4 elems): ((bg*64+h)*66 + wp)*32 + c*4 + q, wp = w+1, -inf borders.
__global__ __launch_bounds__(256) void erode_t(const float* __restrict__ x,
                                               const float* __restrict__ ker,
                                               hv4* __restrict__ ero) {
    // [p*3+r][c][wp0..67]: stride 68 -> c*68 is 16B-aligned (68%4==0), banks <=2-way
    __shared__ __align__(16) float xs[9 * 8 * 68];   // 19584 B

    const int tid = threadIdx.x;
    const int h = blockIdx.x & 63;
    const int g = (blockIdx.x >> 6) & 3;
    const int b = blockIdx.x >> 8;

    const float4* x4 = (const float4*)x;
    const float4* ker4 = (const float4*)ker;

    // stage 3 planes x[(g+p-1)&3], rows h-1..h+1, cols -1..64 (wp 0..65), OOB=+inf
    for (int t = tid; t < 1188; t += 256) {
        int q01 = t & 1;
        int u = t >> 1;
        int wp = u % 66;
        int v = u / 66;
        int r = v % 3;
        int p = v / 3;
        int g2 = (g + p + 3) & 3;
        int h2 = h - 1 + r;
        int w2 = wp - 1;
        float4 vv;
        if ((unsigned)h2 < HH && (unsigned)w2 < WW)
            vv = x4[(((b * 4 + g2) * HH + h2) * WW + w2) * 2 + q01];
        else
            vv = make_float4(POS_INF, POS_INF, POS_INF, POS_INF);
        int rowb = (p * 3 + r) * 8 + q01 * 4;
        xs[(rowb + 0) * 68 + wp] = vv.x;
        xs[(rowb + 1) * 68 + wp] = vv.y;
        xs[(rowb + 2) * 68 + wp] = vv.z;
        xs[(rowb + 3) * 68 + wp] = vv.w;
    }
    __syncthreads();

    const int q = tid & 3;
    const int c = (tid >> 2) & 7;
    const int slot = tid >> 5;
    const float4* xs4 = (const float4*)xs;

    float4 acc[8];
#pragma unroll
    for (int i = 0; i < 8; ++i)
        acc[i] = make_float4(POS_INF, POS_INF, POS_INF, POS_INF);

#pragma unroll
    for (int k2 = 0; k2 < 3; ++k2) {
        // KE_g[dy,dx,k2,c,f4=q] in registers: 9 coalesced 1KB wave reads (L1-hot)
        float4 ke9[9];
#pragma unroll
        for (int t9 = 0; t9 < 9; ++t9) {
            int dy = t9 / 3, dx = t9 % 3;
            int a0 = 2 - dy, b0 = 2 - dx;
            int i, jj;
            ROT_G(g, a0, b0, i, jj);
            int ka, kb, kc;
            if (k2 == 0)      { ka = 2 - jj; kb = i;      kc = 2; }
            else if (k2 == 1) { ka = i;      kb = jj;     kc = 1; }
            else              { ka = jj;     kb = 2 - i;  kc = 0; }
            ke9[t9] = ker4[((ka * 3 + kb) * 3 + kc) * 32 + c * 4 + q];
        }
#pragma unroll
        for (int dy = 0; dy < 3; ++dy) {
            // 12-float window (wp = slot*8 .. slot*8+11) as 3x ds_read_b128
            const int base4 = ((k2 * 3 + dy) * 8 + c) * 17 + slot * 2;
            float4 xa = xs4[base4];
            float4 xb = xs4[base4 + 1];
            float4 xc = xs4[base4 + 2];
            float xw[12] = {xa.x, xa.y, xa.z, xa.w,
                            xb.x, xb.y, xb.z, xb.w,
                            xc.x, xc.y, xc.z, xc.w};
#pragma unroll
            for (int dx = 0; dx < 3; ++dx) {
                float4 kv = ke9[dy * 3 + dx];
#pragma unroll
                for (int i = 0; i < 8; ++i) {
                    float v = xw[i + dx];   // tap wp = slot*8 + i + dx
                    acc[i].x = fminf(acc[i].x, v - kv.x);
                    acc[i].y = fminf(acc[i].y, v - kv.y);
                    acc[i].z = fminf(acc[i].z, v - kv.z);
                    acc[i].w = fminf(acc[i].w, v - kv.w);
                }
            }
        }
    }

    // store: wp = slot*8 + i + 1; lanes (q,c) -> 256B contiguous per (slot,i)
    const int row = (b * 4 + g) * HH + h;
    const size_t obase = ((size_t)row * 66 + slot * 8 + 1) * 32 + c * 4 + q;
#pragma unroll
    for (int i = 0; i < 8; ++i)
        ero[obase + (size_t)i * 32] = f4_to_hv4(acc[i]);

    // -inf border columns wp=0, wp=65 (32 hv4 each)
    const hv4 ninf = {(_Float16)NEG_INF, (_Float16)NEG_INF,
                      (_Float16)NEG_INF, (_Float16)NEG_INF};
    if (tid < 32)
        ero[(size_t)row * 66 * 32 + tid] = ninf;
    else if (tid < 64)
        ero[((size_t)row * 66 + 65) * 32 + (tid - 32)] = ninf;
}

// ======================= kernel 2: dilation (packed f16) ==========================
// block = (b,j,hs,ws); thread = (slot,c,q); w = ws*8+slot, out rows hs*8..hs*8+7.
// Each ero row (10 per strip) loaded once (3 taps) feeds 3 out rows.
__global__ __launch_bounds__(256) void dilate_t(const hv4* __restrict__ ero,
                                                const float* __restrict__ ker,
                                                float* __restrict__ out) {
    const int tid = threadIdx.x;
    const int q = tid & 3;
    const int c = (tid >> 2) & 7;
    const int slot = tid >> 5;
    const int ws = blockIdx.x & 7;
    const int hs = (blockIdx.x >> 3) & 7;
    const int j = (blockIdx.x >> 6) & 3;
    const int b = blockIdx.x >> 8;
    const int w = ws * 8 + slot;

    const float4* ker4 = (const float4*)ker;

    const hv4 ninf = {(_Float16)NEG_INF, (_Float16)NEG_INF,
                      (_Float16)NEG_INF, (_Float16)NEG_INF};
    hv4 acc[8];
#pragma unroll
    for (int r = 0; r < 8; ++r)
        acc[r] = ninf;

#pragma unroll
    for (int k = 0; k < 3; ++k) {
        const int gsrc = (j + k + 3) & 3;
        hv4 kd9[9];
#pragma unroll
        for (int t9 = 0; t9 < 9; ++t9) {
            int dy = t9 / 3, dx = t9 % 3;
            int i, jj;
            ROT_G(j, dy, dx, i, jj);
            kd9[t9] = f4_to_hv4(ker4[((i * 3 + jj) * 3 + k) * 32 + c * 4 + q]);
        }
        // taps at wp = w, w+1, w+2 -> hv4 offsets +0, +32, +64
        const size_t pb = ((size_t)(b * 4 + gsrc) * HH * 66 + w) * 32 + c * 4 + q;
#pragma unroll
        for (int ei = 0; ei < 10; ++ei) {
            const int er = hs * 8 - 1 + ei;
            if ((unsigned)er >= HH) continue;           // wave-uniform
            const size_t rb = pb + (size_t)er * 66 * 32;
            hv4 e0 = ero[rb];
            hv4 e1 = ero[rb + 32];
            hv4 e2 = ero[rb + 64];
#pragma unroll
            for (int dy = 0; dy < 3; ++dy) {
                const int rr = ei - dy;                  // out local row
                if ((unsigned)rr >= 8) continue;
                acc[rr] = __builtin_elementwise_max(acc[rr], e0 + kd9[dy * 3 + 0]);
                acc[rr] = __builtin_elementwise_max(acc[rr], e1 + kd9[dy * 3 + 1]);
                acc[rr] = __builtin_elementwise_max(acc[rr], e2 + kd9[dy * 3 + 2]);
            }
        }
    }

    // c-sum in f32 via xor-shuffle (c = lane bits 2..4), then store
    float4* out4 = (float4*)out;
    const int bjbase = (b * 4 + j) * HH + hs * 8;
#pragma unroll
    for (int r = 0; r < 8; ++r) {
        float4 s = make_float4((float)acc[r].x, (float)acc[r].y,
                               (float)acc[r].z, (float)acc[r].w);
#pragma unroll
        for (int off = 4; off <= 16; off <<= 1) {
            s.x += __shfl_xor(s.x, off, 64);
            s.y += __shfl_xor(s.y, off, 64);
            s.z += __shfl_xor(s.z, off, 64);
            s.w += __shfl_xor(s.w, off, 64);
        }
        if (c == 0)
            out4[((size_t)(bjbase + r) * WW + w) * 4 + q] = s;
    }
}

// ============== fallback: PASSED fused kernel (258 us, R5 prior session) ==========
__global__ __launch_bounds__(256, 3) void opening_fused_fb(
    const float* __restrict__ x, const float* __restrict__ ker, float* __restrict__ out)
{
    __shared__ __align__(16) float xs[8 * 4 * 144];
    __shared__ float4 es4[4 * 4 * 100];
    __shared__ float4 ke4[27 * 4 * 4];
    __shared__ float4 kd4[9 * 4 * 4];

    const int tid = threadIdx.x;
    const int tileX = blockIdx.x & 7;
    const int tileY = (blockIdx.x >> 3) & 7;
    const int j = (blockIdx.x >> 6) & 3;
    const int b = blockIdx.x >> 8;
    const float4* ker4 = (const float4*)ker;
    const float4* x4 = (const float4*)x;

    for (int t = tid; t < 1152; t += 256) {
        int q01 = t & 1;
        int cell = t >> 1;
        int g = cell / 144;
        int rem = cell - g * 144;
        int r = rem / 12;
        int s = rem - r * 12;
        int h = tileY * 8 - 2 + r;
        int w = tileX * 8 - 2 + s;
        float4 v;
        if ((unsigned)h < HH && (unsigned)w < WW)
            v = x4[(((b * 4 + g) * HH + h) * WW + w) * 2 + q01];
        else
            v = make_float4(POS_INF, POS_INF, POS_INF, POS_INF);
        int c0 = q01 * 4;
        xs[((c0 + 0) * 4 + g) * 144 + rem] = v.x;
        xs[((c0 + 1) * 4 + g) * 144 + rem] = v.y;
        xs[((c0 + 2) * 4 + g) * 144 + rem] = v.z;
        xs[((c0 + 3) * 4 + g) * 144 + rem] = v.w;
    }
    __syncthreads();

    const int q_o = tid & 3;
    const int ox = (tid >> 2) & 7;
    const int oy = tid >> 5;

    float4 acc[8];
#pragma unroll
    for (int c = 0; c < 8; ++c)
        acc[c] = make_float4(NEG_INF, NEG_INF, NEG_INF, NEG_INF);

    for (int k = 0; k < 3; ++k) {
        const int gsrc = (j + k + 3) & 3;
#pragma unroll
        for (int cg = 0; cg < 2; ++cg) {
            for (int t = tid; t < 576; t += 256) {
                if (t < 432) {
                    int q = t & 3;
                    int c4 = (t >> 2) & 3;
                    int tap = t >> 4;
                    int k2 = tap % 3;
                    int dxdy = tap / 3;
                    int dx = dxdy % 3;
                    int dy = dxdy / 3;
                    int a0 = 2 - dy, b0 = 2 - dx;
                    int i, jj;
                    ROT_G(gsrc, a0, b0, i, jj);
                    int ka, kb, kc;
                    if (k2 == 0)      { ka = 2 - jj; kb = i;      kc = 2; }
                    else if (k2 == 1) { ka = i;      kb = jj;     kc = 1; }
                    else              { ka = jj;     kb = 2 - i;  kc = 0; }
                    int c = cg * 4 + c4;
                    ke4[t] = ker4[((ka * 3 + kb) * 3 + kc) * 32 + c * 4 + q];
                } else {
                    int u = t - 432;
                    int q = u & 3;
                    int c4 = (u >> 2) & 3;
                    int dydx = u >> 4;
                    int dx = dydx % 3;
                    int dy = dydx / 3;
                    int i, jj;
                    ROT_G(j, dy, dx, i, jj);
                    int c = cg * 4 + c4;
                    kd4[u] = ker4[((i * 3 + jj) * 3 + k) * 32 + c * 4 + q];
                }
            }
            __syncthreads();

            for (int it = 0; it < 2; ++it) {
                int id = tid + (it << 8);
                int c4 = id >> 7;
                int p = id & 127;
                if (p >= 100) continue;
                int ey = (p * 205) >> 11;
                int ex = p - ey * 10;
                int h_es = tileY * 8 - 1 + ey;
                int w_es = tileX * 8 - 1 + ex;
                float4 b0, b1, b2, b3;
                if ((unsigned)h_es < HH && (unsigned)w_es < WW) {
                    b0 = b1 = b2 = b3 = make_float4(POS_INF, POS_INF, POS_INF, POS_INF);
                    int c = cg * 4 + c4;
#pragma unroll
                    for (int k2 = 0; k2 < 3; ++k2) {
                        int g2 = (gsrc + k2 + 3) & 3;
                        int base = (c * 4 + g2) * 144 + ey * 12 + ex;
#pragma unroll
                        for (int dy = 0; dy < 3; ++dy)
#pragma unroll
                            for (int dx = 0; dx < 3; ++dx) {
                                float v = xs[base + dy * 12 + dx];
                                const float4* kk = &ke4[(((dy * 3 + dx) * 3 + k2) * 4 + c4) * 4];
                                float4 kv;
                                kv = kk[0];
                                b0.x = fminf(b0.x, v - kv.x); b0.y = fminf(b0.y, v - kv.y);
                                b0.z = fminf(b0.z, v - kv.z); b0.w = fminf(b0.w, v - kv.w);
                                kv = kk[1];
                                b1.x = fminf(b1.x, v - kv.x); b1.y = fminf(b1.y, v - kv.y);
                                b1.z = fminf(b1.z, v - kv.z); b1.w = fminf(b1.w, v - kv.w);
                                kv = kk[2];
                                b2.x = fminf(b2.x, v - kv.x); b2.y = fminf(b2.y, v - kv.y);
                                b2.z = fminf(b2.z, v - kv.z); b2.w = fminf(b2.w, v - kv.w);
                                kv = kk[3];
                                b3.x = fminf(b3.x, v - kv.x); b3.y = fminf(b3.y, v - kv.y);
                                b3.z = fminf(b3.z, v - kv.z); b3.w = fminf(b3.w, v - kv.w);
                            }
                    }
                } else {
                    b0 = b1 = b2 = b3 = make_float4(NEG_INF, NEG_INF, NEG_INF, NEG_INF);
                }
                int eb = (c4 * 4) * 100 + p;
                es4[eb] = b0; es4[eb + 100] = b1; es4[eb + 200] = b2; es4[eb + 300] = b3;
            }
            __syncthreads();

#pragma unroll
            for (int c4 = 0; c4 < 4; ++c4) {
                float4 a = acc[cg * 4 + c4];
#pragma unroll
                for (int dy = 0; dy < 3; ++dy)
#pragma unroll
                    for (int dx = 0; dx < 3; ++dx) {
                        int pos = (oy + dy) * 10 + (ox + dx);
                        float4 e = es4[(c4 * 4 + q_o) * 100 + pos];
                        float4 kv = kd4[(dy * 3 + dx) * 16 + c4 * 4 + q_o];
                        a.x = fmaxf(a.x, e.x + kv.x);
                        a.y = fmaxf(a.y, e.y + kv.y);
                        a.z = fmaxf(a.z, e.z + kv.z);
                        a.w = fmaxf(a.w, e.w + kv.w);
                    }
                acc[cg * 4 + c4] = a;
            }
            __syncthreads();
        }
    }

    float4 s = acc[0];
#pragma unroll
    for (int c = 1; c < 8; ++c) {
        s.x += acc[c].x; s.y += acc[c].y; s.z += acc[c].z; s.w += acc[c].w;
    }
    const int h = tileY * 8 + oy;
    const int w = tileX * 8 + ox;
    ((float4*)out)[(((b * 4 + j) * HH + h) * WW + w) * 4 + q_o] = s;
}

extern "C" void kernel_launch(void* const* d_in, const int* in_sizes, int n_in,
                              void* d_out, int out_size, void* d_ws, size_t ws_size,
                              hipStream_t stream) {
    const float* x = (const float*)d_in[0];
    const float* ker = (const float*)d_in[1];
    float* out = (float*)d_out;

    const size_t ero_f16_bytes = (size_t)16 * HH * 66 * 32 * 8;   // 17,301,504

    if (ws_size >= ero_f16_bytes) {
        hv4* ero = (hv4*)d_ws;
        erode_t<<<1024, 256, 0, stream>>>(x, ker, ero);
        dilate_t<<<1024, 256, 0, stream>>>(ero, ker, out);
    } else {
        opening_fused_fb<<<1024, 256, 0, stream>>>(x, ker, out);
    }
}